// Round 6
// baseline (253.958 us; speedup 1.0000x reference)
//
#include <hip/hip_runtime.h>

#define NC 3
#define NPC 16
#define NHID 64
#define IMH 128
#define IMW 128
#define CHP 24          // channels per pixel (19 real + 5 zero)
#define PW 134          // padded image width/height (4 halo left/top, 2 right/bottom)
#define PROW (PW*CHP)   // 3216 shorts per padded row
#define PBATCH (PW*PW*CHP)  // shorts per batch image
#define WASZ 4608       // shorts per eval, cols 0..15  (9*4*16*8)
#define WBSZ 13824      // shorts per eval, cols 16..63 (9*4*48*8)

typedef __attribute__((ext_vector_type(8))) short short8;
typedef __attribute__((ext_vector_type(4))) float floatx4;

__device__ __forceinline__ short f2bf(float f) {
    unsigned u = __float_as_uint(f);
    unsigned r = (u + 0x7fff + ((u >> 16) & 1)) >> 16;
    return (short)r;
}

__device__ __forceinline__ short8 zero8() {
    short8 v;
    #pragma unroll
    for (int q = 0; q < 8; ++q) v[q] = 0;
    return v;
}

// 16-lane (DPP row) sum: all lanes end with the row total. VALU pipe, no LDS.
__device__ __forceinline__ float row16sum(float v) {
    v += __int_as_float(__builtin_amdgcn_update_dpp(0, __float_as_int(v), 0x128, 0xf, 0xf, false)); // row_ror:8
    v += __int_as_float(__builtin_amdgcn_update_dpp(0, __float_as_int(v), 0x124, 0xf, 0xf, false)); // row_ror:4
    v += __int_as_float(__builtin_amdgcn_update_dpp(0, __float_as_int(v), 0x122, 0xf, 0xf, false)); // row_ror:2
    v += __int_as_float(__builtin_amdgcn_update_dpp(0, __float_as_int(v), 0x121, 0xf, 0xf, false)); // row_ror:1
    return v;
}

__device__ __forceinline__ void eval_geom(int e, int& sy0, int& sx0, int& cch, int& s_idx) {
    if (e < 3) { sy0 = 0; sx0 = 0; cch = e; s_idx = -1; }
    else {
        int u = e - 3; int s = (u % 9) / 3; cch = u % 3; s_idx = s;
        sy0 = (s == 1) ? 0 : 1;
        sx0 = (s == 2) ? 0 : 1;
    }
}

__device__ __forceinline__ bool tap_active(int e, int ci, int dy, int dx,
                                           int sy0, int sx0, int cch, int s_idx) {
    if (ci >= NC) return true;
    int py = (sy0 + dy - 1) & 1;
    int px = (sx0 + dx - 1) & 1;
    if (e < 3) return (py == 0 && px == 0) && (ci < cch);
    if (py == 0 && px == 0) return true;
    int sp = (py == 1 && px == 1) ? 0 : ((py == 0 && px == 1) ? 1 : 2);
    return (sp < s_idx) || (sp == s_idx && ci < cch);
}

// ---- prepass 1: fp32 NCHW -> zero-padded bf16 channel-last [b][134][134][24] ----
__global__ __launch_bounds__(256) void cvt_kernel(
    const float* __restrict__ value, const float* __restrict__ dp,
    short* __restrict__ imgbf)
{
    const int pix = blockIdx.x * 256 + threadIdx.x;   // over 32*134*134 = 574592
    if (pix >= 32 * PW * PW) return;
    const int b   = pix / (PW * PW);
    const int rem = pix - b * (PW * PW);
    const int y   = rem / PW;
    const int x   = rem - y * PW;
    short* dst = imgbf + (size_t)b * PBATCH + (y * PW + x) * CHP;

    const int yb = y - 4, xb = x - 4;
    if ((unsigned)yb < IMH && (unsigned)xb < IMW) {
        const int o = yb * IMW + xb;
        const float* vb = value + (size_t)b * NC  * 16384 + o;
        const float* pb = dp    + (size_t)b * NPC * 16384 + o;
        short ch[CHP];
        #pragma unroll
        for (int i = 0; i < NC; ++i)  ch[i]      = f2bf(vb[i * 16384]);
        #pragma unroll
        for (int i = 0; i < NPC; ++i) ch[NC + i] = f2bf(pb[i * 16384]);
        #pragma unroll
        for (int i = 19; i < CHP; ++i) ch[i] = 0;
        #pragma unroll
        for (int g = 0; g < 3; ++g) {
            short8 v;
            #pragma unroll
            for (int q = 0; q < 8; ++q) v[q] = ch[g * 8 + q];
            *(short8*)(dst + g * 8) = v;
        }
    } else {
        #pragma unroll
        for (int g = 0; g < 3; ++g) *(short8*)(dst + g * 8) = zero8();
    }
}

// ---- prepass 2: masked bf16 weights, fragment-major; cols 0..15 / 16..63 split ----
__global__ __launch_bounds__(64) void wpk_kernel(
    const float* __restrict__ W1, short* __restrict__ wbfA, short* __restrict__ wbfB)
{
    const int e = blockIdx.x;
    const int n = threadIdx.x;
    int sy0, sx0, cch, s_idx;
    eval_geom(e, sy0, sx0, cch, s_idx);
    const float* wrow = W1 + ((size_t)e * NHID + n) * 171;
    short* dA = wbfA + (size_t)e * WASZ;
    short* dB = wbfB + (size_t)e * WBSZ;
    #pragma unroll
    for (int tap = 0; tap < 9; ++tap) {
        const int dy = tap / 3, dx = tap % 3;
        #pragma unroll
        for (int g = 0; g < 4; ++g) {
            short8 v;
            #pragma unroll
            for (int q = 0; q < 8; ++q) {
                const int ci = g * 8 + q;
                float w = 0.f;
                if (ci < 19 && tap_active(e, ci, dy, dx, sy0, sx0, cch, s_idx))
                    w = wrow[ci * 9 + tap];
                v[q] = f2bf(w);
            }
            if (n < 16) *(short8*)&dA[((tap * 4 + g) * 16 + n) * 8] = v;
            else        *(short8*)&dB[((tap * 4 + g) * 48 + (n - 16)) * 8] = v;
        }
    }
}

// ---- per-level worker: A-fragments direct from global, W-only LDS, no loop barriers ----
template<int EBASE, int SY0, int SX0, int TSH, int RSH, int OWSH, int NOY, int NT>
__device__ __forceinline__ void run_level(
    int bid, int tid, short* Wlds, float* wsum,
    const short* __restrict__ imgbf, const short* __restrict__ wbfA,
    const short* __restrict__ wbfB, const float* __restrict__ b1,
    const float* __restrict__ W2, const float* __restrict__ b2,
    float* __restrict__ out)
{
    constexpr int OW = 1 << OWSH;

    const int c    = bid >> (5 + TSH);
    const int rem  = bid & ((1 << (5 + TSH)) - 1);
    const int b    = rem >> TSH;
    const int tblk = rem & ((1 << TSH) - 1);
    const int e    = EBASE + c;
    const int cch  = c;
    const int oy_start = tblk * (NT * NOY);

    const short* img_b = imgbf + (size_t)b * PBATCH;
    const short* wA    = wbfA + (size_t)e * WASZ;
    const short* wB    = wbfB + (size_t)e * WBSZ;

    const int w    = tid >> 6;
    const int lane = tid & 63;
    const int l15  = lane & 15;
    const int l4   = lane >> 4;

    // ---- stage W cols 16..63 into LDS (1728 16B chunks, linear copy) ----
    #pragma unroll
    for (int i = 0; i < 7; ++i) {
        const int cc = tid + i * 256;
        if (cc < 1728) *(short8*)&Wlds[cc * 8] = *(const short8*)&wB[(size_t)cc * 8];
    }
    // ---- breg: cols 0..15 straight from global (L2-resident) ----
    short8 breg[9];
    #pragma unroll
    for (int tap = 0; tap < 9; ++tap)
        breg[tap] = *(const short8*)&wA[((tap * 4 + l4) * 16 + l15) * 8];

    // ---- epilogue constants ----
    float b1c[4], w2c[4];
    #pragma unroll
    for (int nb = 0; nb < 4; ++nb) {
        const int col = nb * 16 + l15;
        b1c[nb] = b1[e * NHID + col];
        w2c[nb] = W2[e * NHID + col];
    }
    const float bias2 = b2[e];
    const short* wl = &Wlds[(l4 * 48 + l15) * 8];

    __syncthreads();              // W visible; only barrier before the loop

    float lpsum = 0.f;

    for (int t = 0; t < NT; ++t) {
        // per-lane A base addresses for this tile (2 row-fragments per wave)
        const short* pA[2];
        #pragma unroll
        for (int a = 0; a < 2; ++a) {
            const int rowA = w * 32 + a * 16 + l15;
            const int oyr  = rowA >> OWSH;
            const int ox   = rowA & (OW - 1);
            const int y0   = SY0 + 2 * (oy_start + t * NOY + oyr);
            const int x0   = SX0 + 2 * ox;
            pA[a] = img_b + ((y0 << RSH) + 4) * PROW + ((x0 << RSH) + 4) * CHP + l4 * 8;
        }

        floatx4 acc[2][4];
        #pragma unroll
        for (int a = 0; a < 2; ++a)
            #pragma unroll
            for (int nb = 0; nb < 4; ++nb)
                acc[a][nb] = (floatx4){0.f, 0.f, 0.f, 0.f};

        #pragma unroll
        for (int tap = 0; tap < 9; ++tap) {
            const int dy  = tap / 3, dx = tap % 3;
            const int dlt = ((dy - 1) << RSH) * PROW + (((dx - 1) << RSH) * CHP); // compile-time
            short8 a0  = *(const short8*)(pA[0] + dlt);
            short8 a1  = *(const short8*)(pA[1] + dlt);
            short8 b1f = *(const short8*)&wl[tap * 1536];
            short8 b2f = *(const short8*)&wl[tap * 1536 + 128];
            short8 b3f = *(const short8*)&wl[tap * 1536 + 256];
            acc[0][0] = __builtin_amdgcn_mfma_f32_16x16x32_bf16(a0, breg[tap], acc[0][0], 0, 0, 0);
            acc[1][0] = __builtin_amdgcn_mfma_f32_16x16x32_bf16(a1, breg[tap], acc[1][0], 0, 0, 0);
            acc[0][1] = __builtin_amdgcn_mfma_f32_16x16x32_bf16(a0, b1f, acc[0][1], 0, 0, 0);
            acc[1][1] = __builtin_amdgcn_mfma_f32_16x16x32_bf16(a1, b1f, acc[1][1], 0, 0, 0);
            acc[0][2] = __builtin_amdgcn_mfma_f32_16x16x32_bf16(a0, b2f, acc[0][2], 0, 0, 0);
            acc[1][2] = __builtin_amdgcn_mfma_f32_16x16x32_bf16(a1, b2f, acc[1][2], 0, 0, 0);
            acc[0][3] = __builtin_amdgcn_mfma_f32_16x16x32_bf16(a0, b3f, acc[0][3], 0, 0, 0);
            acc[1][3] = __builtin_amdgcn_mfma_f32_16x16x32_bf16(a1, b3f, acc[1][3], 0, 0, 0);
        }

        // ---- epilogue: z per row, half-wave parallel logsig ----
        float zv[8];
        #pragma unroll
        for (int a = 0; a < 2; ++a) {
            #pragma unroll
            for (int j = 0; j < 4; ++j) {
                float part = 0.f;
                #pragma unroll
                for (int nb = 0; nb < 4; ++nb)
                    part += w2c[nb] * fmaxf(acc[a][nb][j] + b1c[nb], 0.f);
                zv[a * 4 + j] = row16sum(part);
            }
        }

        if (l15 < 8) {
            const float s01 = (l15 & 1) ? zv[1] : zv[0];
            const float s23 = (l15 & 1) ? zv[3] : zv[2];
            const float s45 = (l15 & 1) ? zv[5] : zv[4];
            const float s67 = (l15 & 1) ? zv[7] : zv[6];
            const float s03 = (l15 & 2) ? s23 : s01;
            const float s47 = (l15 & 2) ? s67 : s45;
            const float zs  = ((l15 & 4) ? s47 : s03) + bias2;
            const int rwg    = w * 32 + ((l15 >> 2) << 4) + (l4 << 2) + (l15 & 3);
            const int oy_rel = rwg >> OWSH;
            const int oxj    = rwg & (OW - 1);
            const int yj     = SY0 + 2 * (oy_start + t * NOY + oy_rel);
            const int xj     = SX0 + 2 * oxj;
            const unsigned short hv =
                *(const unsigned short*)&img_b[((yj << RSH) + 4) * PROW + ((xj << RSH) + 4) * CHP + cch];
            const float xv = __uint_as_float(((unsigned)hv) << 16);
            const float az  = fabsf(zs);
            const float t2  = __builtin_amdgcn_exp2f(-1.442695041f * az);
            const float l1p = 0.69314718056f * __builtin_amdgcn_logf(1.f + t2);
            lpsum += xv * zs + fminf(-zs, 0.f) - l1p;
        }
    }

    // ---- block reduce ----
    lpsum += __shfl_down(lpsum, 32);
    lpsum += __shfl_down(lpsum, 16);
    lpsum += __shfl_down(lpsum, 8);
    lpsum += __shfl_down(lpsum, 4);
    lpsum += __shfl_down(lpsum, 2);
    lpsum += __shfl_down(lpsum, 1);
    if (lane == 0) wsum[w] = lpsum;
    __syncthreads();
    if (tid == 0) atomicAdd(out, wsum[0] + wsum[1] + wsum[2] + wsum[3]);
}

// ---- merged kernel: 7 parity-class instantiations, fine first ----
__global__ __launch_bounds__(256, 4) void pcnn_all(
    const short* __restrict__ imgbf, const short* __restrict__ wbfA,
    const short* __restrict__ wbfB, const float* __restrict__ b1,
    const float* __restrict__ W2, const float* __restrict__ b2,
    float* __restrict__ out)
{
    __shared__ __align__(16) short Wlds[1728 * 8];   // 27648 B
    __shared__ float wsum[4];
    const int bid = blockIdx.x;
    const int tid = threadIdx.x;

    //            EBASE SY SX TSH RSH OWSH NOY NT
    if (bid < 768)
        run_level<12, 1, 1, 3, 0, 6, 2, 4>(bid,        tid, Wlds, wsum, imgbf, wbfA, wbfB, b1, W2, b2, out);
    else if (bid < 1536)
        run_level<15, 0, 1, 3, 0, 6, 2, 4>(bid - 768,  tid, Wlds, wsum, imgbf, wbfA, wbfB, b1, W2, b2, out);
    else if (bid < 2304)
        run_level<18, 1, 0, 3, 0, 6, 2, 4>(bid - 1536, tid, Wlds, wsum, imgbf, wbfA, wbfB, b1, W2, b2, out);
    else if (bid < 2496)
        run_level<3,  1, 1, 1, 1, 5, 4, 4>(bid - 2304, tid, Wlds, wsum, imgbf, wbfA, wbfB, b1, W2, b2, out);
    else if (bid < 2688)
        run_level<6,  0, 1, 1, 1, 5, 4, 4>(bid - 2496, tid, Wlds, wsum, imgbf, wbfA, wbfB, b1, W2, b2, out);
    else if (bid < 2880)
        run_level<9,  1, 0, 1, 1, 5, 4, 4>(bid - 2688, tid, Wlds, wsum, imgbf, wbfA, wbfB, b1, W2, b2, out);
    else
        run_level<0,  0, 0, 0, 2, 4, 8, 2>(bid - 2880, tid, Wlds, wsum, imgbf, wbfA, wbfB, b1, W2, b2, out);
}

extern "C" void kernel_launch(void* const* d_in, const int* in_sizes, int n_in,
                              void* d_out, int out_size, void* d_ws, size_t ws_size,
                              hipStream_t stream) {
    const float* value = (const float*)d_in[0];
    const float* dp    = (const float*)d_in[1];
    const float* W1    = (const float*)d_in[2];
    const float* b1    = (const float*)d_in[3];
    const float* W2    = (const float*)d_in[4];
    const float* b2    = (const float*)d_in[5];
    float* out = (float*)d_out;

    short* imgbf = (short*)d_ws;                          // 32*134*134*24*2 = 27.6 MB
    short* wbfA  = imgbf + (size_t)32 * PBATCH;           // 21*4608  shorts
    short* wbfB  = wbfA + (size_t)21 * WASZ;              // 21*13824 shorts

    hipMemsetAsync(out, 0, sizeof(float), stream);
    hipLaunchKernelGGL(cvt_kernel, dim3((32 * PW * PW + 255) / 256), dim3(256), 0, stream,
                       value, dp, imgbf);
    hipLaunchKernelGGL(wpk_kernel, dim3(21), dim3(64), 0, stream, W1, wbfA, wbfB);
    hipLaunchKernelGGL(pcnn_all, dim3(2976), dim3(256), 0, stream,
                       imgbf, wbfA, wbfB, b1, W2, b2, out);
}

// Round 7
// 113.497 us; speedup vs baseline: 2.2376x; 2.2376x over previous
//
#include <hip/hip_runtime.h>

typedef unsigned char uchar;
typedef unsigned long long ull;
typedef __attribute__((ext_vector_type(2))) unsigned long long ullx2;
typedef __attribute__((ext_vector_type(4))) float floatx4;
typedef __attribute__((ext_vector_type(4))) unsigned int uintx4;

#define NB_IMG 18496      // 136 y * 2 p * 68 xh pixel slots per batch image
#define WEVAL 9216        // bytes per eval per weight half
#define AREG 29376        // A-tile LDS bytes (1224 px * 24 B)

// ---- fp32 -> fp8 e4m3 (OCP), RNE ----
__device__ __forceinline__ uchar f2e4(float x) {
    float a = fabsf(x);
    unsigned s = (__float_as_uint(x) >> 24) & 0x80u;
    if (a >= 448.f) return (uchar)(s | 0x7E);
    if (a < 0.015625f) {                       // denormal: m = round(a * 2^9)
        int m = (int)rintf(a * 512.f);
        return (uchar)(s | (unsigned)m);       // m==8 encodes 2^-6 exactly
    }
    unsigned u = __float_as_uint(a);
    unsigned r = u + 0x7FFFFu + ((u >> 20) & 1u);   // RNE into 3-bit mantissa
    unsigned e8 = (r >> 23) - 120u;
    return (uchar)(s | (e8 << 3) | ((r >> 20) & 7u));
}

// 16-lane DPP row sum (all lanes get row total)
__device__ __forceinline__ float row16sum(float v) {
    v += __int_as_float(__builtin_amdgcn_update_dpp(0, __float_as_int(v), 0x128, 0xf, 0xf, false));
    v += __int_as_float(__builtin_amdgcn_update_dpp(0, __float_as_int(v), 0x124, 0xf, 0xf, false));
    v += __int_as_float(__builtin_amdgcn_update_dpp(0, __float_as_int(v), 0x122, 0xf, 0xf, false));
    v += __int_as_float(__builtin_amdgcn_update_dpp(0, __float_as_int(v), 0x121, 0xf, 0xf, false));
    return v;
}

__device__ __forceinline__ void eval_geom(int e, int& sy0, int& sx0, int& cch, int& s_idx) {
    if (e < 3) { sy0 = 0; sx0 = 0; cch = e; s_idx = -1; }
    else {
        int u = e - 3; int s = (u % 9) / 3; cch = u % 3; s_idx = s;
        sy0 = (s == 1) ? 0 : 1;
        sx0 = (s == 2) ? 0 : 1;
    }
}

__device__ __forceinline__ bool tap_active(int e, int ci, int dy, int dx,
                                           int sy0, int sx0, int cch, int s_idx) {
    if (ci >= 3) return true;
    int py = (sy0 + dy - 1) & 1;
    int px = (sx0 + dx - 1) & 1;
    if (e < 3) return (py == 0 && px == 0) && (ci < cch);
    if (py == 0 && px == 0) return true;
    int sp = (py == 1 && px == 1) ? 0 : ((py == 0 && px == 1) ? 1 : 2);
    return (sp < s_idx) || (sp == s_idx && ci < cch);
}

// ---- prepass 1: fp32 NCHW -> fp8 parity-split padded [b][y 136][p 2][xh 68][32B] ----
__global__ __launch_bounds__(256) void cvt_kernel(
    const float* __restrict__ value, const float* __restrict__ dp,
    uchar* __restrict__ imgbf)
{
    const int t = blockIdx.x * 256 + threadIdx.x;   // 591872 slots
    const int b = t / NB_IMG;
    const int r = t - b * NB_IMG;
    const int y = r / 136;
    const int rr = r - y * 136;
    const int p = rr / 68;
    const int xh = rr - p * 68;
    const int yi = y - 4;
    const int xi = 2 * (xh - 2) + p;
    unsigned d[8];
    #pragma unroll
    for (int i = 0; i < 8; ++i) d[i] = 0;
    if ((unsigned)yi < 128u && (unsigned)xi < 128u) {
        const int o = yi * 128 + xi;
        const float* vb = value + (size_t)b * 3 * 16384 + o;
        const float* pb = dp + (size_t)b * 16 * 16384 + o;
        #pragma unroll
        for (int i = 0; i < 3; ++i) d[i >> 2] |= (unsigned)f2e4(vb[i * 16384]) << ((i & 3) * 8);
        #pragma unroll
        for (int i = 0; i < 16; ++i) {
            const int ci = 3 + i;
            d[ci >> 2] |= (unsigned)f2e4(pb[i * 16384]) << ((ci & 3) * 8);
        }
    }
    uchar* dst = imgbf + (size_t)t * 32;
    uintx4 v0, v1;
    v0[0] = d[0]; v0[1] = d[1]; v0[2] = d[2]; v0[3] = d[3];
    v1[0] = d[4]; v1[1] = d[5]; v1[2] = d[6]; v1[3] = d[7];
    *(uintx4*)dst = v0;
    *(uintx4*)(dst + 16) = v1;
}

// ---- prepass 2: masked fp8 weights, fragment-major [e][tap][g][n][8B]; cols 0-31 / 32-63 ----
__global__ __launch_bounds__(64) void wpk_kernel(
    const float* __restrict__ W1, uchar* __restrict__ wbfA, uchar* __restrict__ wbfB)
{
    const int e = blockIdx.x;
    const int n = threadIdx.x;
    int sy0, sx0, cch, s_idx;
    eval_geom(e, sy0, sx0, cch, s_idx);
    const float* wrow = W1 + ((size_t)e * 64 + n) * 171;
    uchar* dA = wbfA + (size_t)e * WEVAL;
    uchar* dB = wbfB + (size_t)e * WEVAL;
    #pragma unroll
    for (int tap = 0; tap < 9; ++tap) {
        const int dy = tap / 3, dx = tap % 3;
        #pragma unroll
        for (int g = 0; g < 4; ++g) {
            ull v = 0;
            #pragma unroll
            for (int q = 0; q < 8; ++q) {
                const int ci = g * 8 + q;
                float w = 0.f;
                if (ci < 19 && tap_active(e, ci, dy, dx, sy0, sx0, cch, s_idx))
                    w = wrow[ci * 9 + tap];
                v |= (ull)f2e4(w) << (q * 8);
            }
            if (n < 32) *(ull*)&dA[((tap * 4 + g) * 32 + n) * 8] = v;
            else        *(ull*)&dB[((tap * 4 + g) * 32 + (n - 32)) * 8] = v;
        }
    }
}

__device__ __forceinline__ void stage_w(int tid, uchar* dst, const uchar* wbfB, int e) {
    const uchar* src = wbfB + (size_t)e * WEVAL;
    #pragma unroll
    for (int i = 0; i < 3; ++i) {
        const int c = tid + i * 256;
        if (c < 576) *(ullx2*)(dst + c * 16) = *(const ullx2*)(src + c * 16);
    }
}

// ---- one parity class: 3 channel evals sharing the A-tile; W double-buffered ----
template<int SY0, int SX0, int RSH, int OWSH, int TXH>
__device__ __forceinline__ void class_body(
    int e0, int e_after, int& buf, float& lpsum,
    int b, int oy0, int ox0, int tid,
    uchar* Alds, uchar* Wb0, uchar* Wb1,
    const uchar* wbfA, const uchar* wbfB,
    const float* __restrict__ value, const float* __restrict__ b1,
    const float* __restrict__ W2, const float* __restrict__ b2)
{
    constexpr int OW = 1 << OWSH;
    const int w = tid >> 6, lane = tid & 63, l15 = lane & 15, l4 = lane >> 4;
    int abase[4];
    #pragma unroll
    for (int a = 0; a < 4; ++a) {
        const int row = w * 64 + a * 16 + l15;
        const int oy = row >> OWSH, ox = row & (OW - 1);
        abase[a] = ((SY0 + 2 * oy) * 2 * TXH + ox) * 24 + l4 * 8;
    }
    const int wfb = l4 * 256 + l15 * 8;

    #pragma unroll 1
    for (int c = 0; c < 3; ++c) {
        const int e = e0 + c;
        __syncthreads();                 // prev W reads done; (first time) A visible
        uchar* Wcur = buf ? Wb1 : Wb0;
        uchar* Wnxt = buf ? Wb0 : Wb1;
        const int en = (c < 2) ? (e + 1) : e_after;
        if (en >= 0) stage_w(tid, Wnxt, wbfB, en);   // prefetch next eval's W half

        const uchar* wA = wbfA + (size_t)e * WEVAL;
        ull breg[9][2];
        #pragma unroll
        for (int tap = 0; tap < 9; ++tap) {
            breg[tap][0] = *(const ull*)(wA + (tap * 1024 + wfb));
            breg[tap][1] = *(const ull*)(wA + (tap * 1024 + wfb + 128));
        }
        float b1c[4], w2c[4];
        #pragma unroll
        for (int nb = 0; nb < 4; ++nb) {
            b1c[nb] = b1[e * 64 + nb * 16 + l15];
            w2c[nb] = W2[e * 64 + nb * 16 + l15];
        }
        const float bias2 = b2[e];

        floatx4 acc[4][4];
        #pragma unroll
        for (int a = 0; a < 4; ++a)
            #pragma unroll
            for (int nb = 0; nb < 4; ++nb)
                acc[a][nb] = (floatx4){0.f, 0.f, 0.f, 0.f};

        #pragma unroll
        for (int tap = 0; tap < 9; ++tap) {
            const int dy = tap / 3, dx = tap % 3;
            const int v = SX0 + dx + 1;
            const int D = (2 * dy + (v & 1)) * TXH + (v >> 1);   // compile-time px delta
            ull av[4];
            #pragma unroll
            for (int a = 0; a < 4; ++a)
                av[a] = *(const ull*)(Alds + abase[a] + D * 24);
            const ull bv2 = *(const ull*)(Wcur + wfb + tap * 1024);
            const ull bv3 = *(const ull*)(Wcur + wfb + tap * 1024 + 128);
            #pragma unroll
            for (int a = 0; a < 4; ++a) {
                acc[a][0] = __builtin_amdgcn_mfma_f32_16x16x32_fp8_fp8((long)av[a], (long)breg[tap][0], acc[a][0], 0, 0, 0);
                acc[a][1] = __builtin_amdgcn_mfma_f32_16x16x32_fp8_fp8((long)av[a], (long)breg[tap][1], acc[a][1], 0, 0, 0);
                acc[a][2] = __builtin_amdgcn_mfma_f32_16x16x32_fp8_fp8((long)av[a], (long)bv2, acc[a][2], 0, 0, 0);
                acc[a][3] = __builtin_amdgcn_mfma_f32_16x16x32_fp8_fp8((long)av[a], (long)bv3, acc[a][3], 0, 0, 0);
            }
        }

        // ---- epilogue: 16 row-sums; every lane handles one of the wave's 64 rows ----
        float zv[16];
        #pragma unroll
        for (int a = 0; a < 4; ++a)
            #pragma unroll
            for (int j = 0; j < 4; ++j) {
                float part = 0.f;
                #pragma unroll
                for (int nb = 0; nb < 4; ++nb)
                    part += w2c[nb] * fmaxf(acc[a][nb][j] + b1c[nb], 0.f);
                zv[a * 4 + j] = row16sum(part);
            }
        const float u0 = (l15 & 1) ? zv[1] : zv[0];
        const float u1 = (l15 & 1) ? zv[3] : zv[2];
        const float u2 = (l15 & 1) ? zv[5] : zv[4];
        const float u3 = (l15 & 1) ? zv[7] : zv[6];
        const float u4 = (l15 & 1) ? zv[9] : zv[8];
        const float u5 = (l15 & 1) ? zv[11] : zv[10];
        const float u6 = (l15 & 1) ? zv[13] : zv[12];
        const float u7 = (l15 & 1) ? zv[15] : zv[14];
        const float p0 = (l15 & 2) ? u1 : u0;
        const float p1 = (l15 & 2) ? u3 : u2;
        const float p2 = (l15 & 2) ? u5 : u4;
        const float p3 = (l15 & 2) ? u7 : u6;
        const float q0 = (l15 & 4) ? p1 : p0;
        const float q1 = (l15 & 4) ? p3 : p2;
        const float zs = ((l15 & 8) ? q1 : q0) + bias2;
        const int row = w * 64 + ((l15 >> 2) << 4) + (l4 << 2) + (l15 & 3);
        const int oyj = oy0 + (row >> OWSH);
        const int oxj = ox0 + (row & (OW - 1));
        const int yj = (SY0 + 2 * oyj) << RSH;
        const int xj = (SX0 + 2 * oxj) << RSH;
        const float xv = value[((size_t)b * 3 + c) * 16384 + yj * 128 + xj];
        const float az = fabsf(zs);
        const float t2 = __builtin_amdgcn_exp2f(-1.442695041f * az);
        const float l1p = 0.69314718056f * __builtin_amdgcn_logf(1.f + t2);
        lpsum += xv * zs + fminf(-zs, 0.f) - l1p;
        buf ^= 1;
    }
}

template<int EB, int RSH, int OWSH, int TXH, int TY, int NCLS>
__device__ __forceinline__ void run_level(
    int b, int oy0, int ox0, int tid,
    uchar* Alds, uchar* Wb0, uchar* Wb1, float* wsum,
    const uchar* __restrict__ imgbf, const uchar* __restrict__ wbfA,
    const uchar* __restrict__ wbfB, const float* __restrict__ value,
    const float* __restrict__ b1, const float* __restrict__ W2,
    const float* __restrict__ b2, float* __restrict__ out)
{
    constexpr int TPIX = TY * 2 * TXH;
    const int lane = tid & 63, w = tid >> 6;

    // ---- stage A-tile (fp8, 24 B/px), shared by all evals of this block ----
    const int yb = 2 * oy0 - 1, xb = 2 * ox0 - 2;
    const uchar* img_b = imgbf + (size_t)b * ((size_t)NB_IMG * 32);
    #pragma unroll
    for (int i = 0; i < (TPIX + 255) / 256; ++i) {
        const int px = tid + i * 256;
        if (px < TPIX) {
            const int typ = px / TXH;
            const int xh = px - typ * TXH;
            const int yl = yb + (typ >> 1);
            const int xl = xb + 2 * xh + (typ & 1);
            int yi = (yl << RSH) + 4; yi = yi < 0 ? 0 : (yi > 135 ? 135 : yi);
            int xi = (xl << RSH) + 4; xi = xi < 0 ? 0 : (xi > 135 ? 135 : xi);
            const uchar* src = img_b + (size_t)(yi * 136 + (xi & 1) * 68 + (xi >> 1)) * 32;
            ullx2 v01 = *(const ullx2*)src;
            ull v2 = *(const ull*)(src + 16);
            uchar* dst = Alds + px * 24;
            *(ull*)dst = v01[0];
            *(ull*)(dst + 8) = v01[1];
            *(ull*)(dst + 16) = v2;
        }
    }
    if constexpr (TPIX * 24 + 32 <= AREG) {         // guard l4=3 spill past tile (base level)
        if (tid < 4) *(ull*)(Alds + TPIX * 24 + tid * 8) = 0ull;
    }

    int buf = 0;
    stage_w(tid, Wb0, wbfB, EB);     // first eval's W half
    float lpsum = 0.f;
    if constexpr (NCLS == 3) {
        class_body<1, 1, RSH, OWSH, TXH>(EB + 0, EB + 3, buf, lpsum, b, oy0, ox0, tid, Alds, Wb0, Wb1, wbfA, wbfB, value, b1, W2, b2);
        class_body<0, 1, RSH, OWSH, TXH>(EB + 3, EB + 6, buf, lpsum, b, oy0, ox0, tid, Alds, Wb0, Wb1, wbfA, wbfB, value, b1, W2, b2);
        class_body<1, 0, RSH, OWSH, TXH>(EB + 6, -1, buf, lpsum, b, oy0, ox0, tid, Alds, Wb0, Wb1, wbfA, wbfB, value, b1, W2, b2);
    } else {
        class_body<0, 0, RSH, OWSH, TXH>(EB, -1, buf, lpsum, b, oy0, ox0, tid, Alds, Wb0, Wb1, wbfA, wbfB, value, b1, W2, b2);
    }

    lpsum += __shfl_down(lpsum, 32);
    lpsum += __shfl_down(lpsum, 16);
    lpsum += __shfl_down(lpsum, 8);
    lpsum += __shfl_down(lpsum, 4);
    lpsum += __shfl_down(lpsum, 2);
    lpsum += __shfl_down(lpsum, 1);
    if (lane == 0) wsum[w] = lpsum;
    __syncthreads();
    if (tid == 0) atomicAdd(out, wsum[0] + wsum[1] + wsum[2] + wsum[3]);
}

__global__ __launch_bounds__(256, 3) void pcnn_all(
    const uchar* __restrict__ imgbf, const uchar* __restrict__ wbfA,
    const uchar* __restrict__ wbfB, const float* __restrict__ value,
    const float* __restrict__ b1, const float* __restrict__ W2,
    const float* __restrict__ b2, float* __restrict__ out)
{
    __shared__ __align__(16) uchar smem[AREG + 2 * WEVAL];
    __shared__ float wsum[4];
    uchar* Alds = smem;
    uchar* Wb0 = smem + AREG;
    uchar* Wb1 = smem + AREG + WEVAL;
    const int bid = blockIdx.x, tid = threadIdx.x;

    if (bid < 512) {                       // fine: e 12..20, r=1; region = 8oy x 32ox
        const int b = bid >> 4, rr = bid & 15;
        run_level<12, 0, 5, 34, 18, 3>(b, (rr >> 1) * 8, (rr & 1) * 32, tid, Alds, Wb0, Wb1, wsum,
                                       imgbf, wbfA, wbfB, value, b1, W2, b2, out);
    } else if (bid < 640) {                // mid: e 3..11, r=2; region = 8oy x 32ox (full width)
        const int u = bid - 512;
        run_level<3, 1, 5, 34, 18, 3>(u >> 2, (u & 3) * 8, 0, tid, Alds, Wb0, Wb1, wsum,
                                      imgbf, wbfA, wbfB, value, b1, W2, b2, out);
    } else {                               // base: e 0..2, r=4; whole 16x16 grid
        const int u = bid - 640;
        run_level<0, 2, 4, 17, 33, 1>(u, 0, 0, tid, Alds, Wb0, Wb1, wsum,
                                      imgbf, wbfA, wbfB, value, b1, W2, b2, out);
    }
}

extern "C" void kernel_launch(void* const* d_in, const int* in_sizes, int n_in,
                              void* d_out, int out_size, void* d_ws, size_t ws_size,
                              hipStream_t stream) {
    const float* value = (const float*)d_in[0];
    const float* dp    = (const float*)d_in[1];
    const float* W1    = (const float*)d_in[2];
    const float* b1    = (const float*)d_in[3];
    const float* W2    = (const float*)d_in[4];
    const float* b2    = (const float*)d_in[5];
    float* out = (float*)d_out;

    uchar* imgbf = (uchar*)d_ws;                                  // 32*18496*32 = 18.94 MB
    uchar* wbfA  = imgbf + (size_t)32 * NB_IMG * 32;              // 21*9216 B
    uchar* wbfB  = wbfA + (size_t)21 * WEVAL;                     // 21*9216 B

    hipMemsetAsync(out, 0, sizeof(float), stream);
    hipLaunchKernelGGL(cvt_kernel, dim3(2312), dim3(256), 0, stream, value, dp, imgbf);
    hipLaunchKernelGGL(wpk_kernel, dim3(21), dim3(64), 0, stream, W1, wbfA, wbfB);
    hipLaunchKernelGGL(pcnn_all, dim3(672), dim3(256), 0, stream,
                       imgbf, wbfA, wbfB, value, b1, W2, b2, out);
}